// Round 1
// baseline (318.728 us; speedup 1.0000x reference)
//
#include <hip/hip_runtime.h>

#define T_CNT 128
#define IOU_TH 0.4f
#define K_CONST 2.5f
#define PPT 4  // priors per thread

// ws layout:
//   [0,32)        double accum[4]: S1=sum(sig), S2=sum(xf), S3=sum(sig*xf*log(bto))
//   [64,1088)     unsigned long long packed[128]: (iou_bits<<32) | ~prior_idx
//   [4096, +P*4)  float bto[P]
static const size_t WS_ACC_OFF = 0;
static const size_t WS_PACKED_OFF = 64;
static const size_t WS_BTO_OFF = 4096;

__device__ inline unsigned long long shflxor_u64(unsigned long long v, int m) {
    unsigned int lo = (unsigned int)v;
    unsigned int hi = (unsigned int)(v >> 32);
    lo = __shfl_xor(lo, m, 64);
    hi = __shfl_xor(hi, m, 64);
    return ((unsigned long long)hi << 32) | lo;
}

__global__ __launch_bounds__(256) void apb_main(
    const float* __restrict__ locs, const float* __restrict__ params,
    const float* __restrict__ truths, float* __restrict__ bto,
    unsigned long long* __restrict__ packed, double* __restrict__ accum)
{
    __shared__ float4 s_tb[T_CNT];   // truth corner form
    __shared__ float  s_ta[T_CNT];   // truth area

    const int tid = threadIdx.x;
    for (int t = tid; t < T_CNT; t += 256) {
        float4 tb = ((const float4*)truths)[t];
        s_tb[t] = tb;
        s_ta[t] = (tb.z - tb.x) * (tb.w - tb.y);
    }
    __syncthreads();

    const int base = blockIdx.x * (256 * PPT);

    // Load PPT priors per thread into registers (coalesced: p = base + k*256 + tid)
    float px1[PPT], py1[PPT], px2[PPT], py2[PPT], parea[PPT];
    unsigned long long plow[PPT];
#pragma unroll
    for (int k = 0; k < PPT; ++k) {
        int p = base + k * 256 + tid;
        float2 c = ((const float2*)locs)[p];
        float w = params[3 * p];
        float h = params[3 * p + 1];
        float hw = 0.5f * w, hh = 0.5f * h;
        px1[k] = c.x - hw; py1[k] = c.y - hh;
        px2[k] = c.x + hw; py2[k] = c.y + hh;
        parea[k] = (px2[k] - px1[k]) * (py2[k] - py1[k]);
        plow[k] = (unsigned long long)(~(unsigned int)p);
    }

    float btmax[PPT];
#pragma unroll
    for (int k = 0; k < PPT; ++k) btmax[k] = 0.f;

#pragma unroll 4
    for (int t = 0; t < T_CNT; ++t) {
        float4 tb = s_tb[t];
        float  ta = s_ta[t];
        unsigned long long best = 0ull;
#pragma unroll
        for (int k = 0; k < PPT; ++k) {
            float lx = fmaxf(tb.x, px1[k]);
            float ly = fmaxf(tb.y, py1[k]);
            float rx = fminf(tb.z, px2[k]);
            float ry = fminf(tb.w, py2[k]);
            float w = fmaxf(rx - lx, 0.f);
            float h = fmaxf(ry - ly, 0.f);
            float inter = w * h;
            float denom = (ta + parea[k]) - inter;
            float iou = inter * __builtin_amdgcn_rcpf(denom);
            btmax[k] = fmaxf(btmax[k], iou);
            unsigned long long v =
                ((unsigned long long)__float_as_uint(iou) << 32) | plow[k];
            best = (v > best) ? v : best;
        }
        // wave-level max reduce of packed (iou, ~p)
#pragma unroll
        for (int off = 32; off; off >>= 1) {
            unsigned long long o = shflxor_u64(best, off);
            best = (o > best) ? o : best;
        }
        if ((tid & 63) == 0) atomicMax(&packed[t], best);
    }

    // Epilogue: per-prior loss terms (pre-scatter baseline)
    float s1 = 0.f, s2 = 0.f, s3 = 0.f;
#pragma unroll
    for (int k = 0; k < PPT; ++k) {
        int p = base + k * 256 + tid;
        float a = params[3 * p + 2];
        float sig = 1.f / (1.f + expf(-a));
        float bt = btmax[k];
        float xf = (bt > IOU_TH) ? 1.f : 0.f;
        s1 += sig;
        s2 += xf;
        s3 += (xf > 0.f) ? sig * logf(bt) : 0.f;
        bto[p] = bt;
    }
#pragma unroll
    for (int off = 32; off; off >>= 1) {
        s1 += __shfl_xor(s1, off, 64);
        s2 += __shfl_xor(s2, off, 64);
        s3 += __shfl_xor(s3, off, 64);
    }
    if ((tid & 63) == 0) {
        atomicAdd(&accum[0], (double)s1);
        atomicAdd(&accum[1], (double)s2);
        atomicAdd(&accum[2], (double)s3);
    }
}

__global__ __launch_bounds__(128) void apb_final(
    const float* __restrict__ params, const float* __restrict__ bto,
    const unsigned long long* __restrict__ packed,
    const double* __restrict__ accum, float* __restrict__ out)
{
    const int t = threadIdx.x;
    __shared__ unsigned int s_idx[T_CNT];

    unsigned long long v = packed[t];
    float ov = __uint_as_float((unsigned int)(v >> 32));     // best_prior_overlap[t]
    unsigned int p = ~(unsigned int)(v & 0xFFFFFFFFull);     // best_prior_idx[t]
    s_idx[t] = p;
    __syncthreads();

    // numpy fancy-assignment semantics: for duplicate indices, last t wins
    bool is_last = true;
    for (int u = t + 1; u < T_CNT; ++u)
        if (s_idx[u] == p) is_last = false;

    float c2 = 0.f, c3 = 0.f;
    if (is_last) {
        float old = bto[p];
        float oxf = (old > IOU_TH) ? 1.f : 0.f;
        float a = params[3 * p + 2];
        float sig = 1.f / (1.f + expf(-a));
        float oldterm = (oxf > 0.f) ? sig * logf(old) : 0.f;
        float newterm = K_CONST * sig * logf(ov);
        c3 = newterm - oldterm;
        c2 = K_CONST - oxf;
    }

    // reduce corrections over 128 threads (2 waves)
#pragma unroll
    for (int off = 32; off; off >>= 1) {
        c2 += __shfl_xor(c2, off, 64);
        c3 += __shfl_xor(c3, off, 64);
    }
    __shared__ float sw[4];
    if ((t & 63) == 0) { sw[(t >> 6) * 2] = c2; sw[(t >> 6) * 2 + 1] = c3; }
    __syncthreads();

    if (t == 0) {
        double S1 = accum[0];
        double S2 = accum[1] + (double)(sw[0] + sw[2]);
        double S3 = accum[2] + (double)(sw[1] + sw[3]);
        out[0] = (float)((S1 - S3) / S2);  // BETA = 1.0
    }
}

extern "C" void kernel_launch(void* const* d_in, const int* in_sizes, int n_in,
                              void* d_out, int out_size, void* d_ws, size_t ws_size,
                              hipStream_t stream) {
    const float* locs   = (const float*)d_in[0];
    const float* params = (const float*)d_in[1];
    const float* truths = (const float*)d_in[2];
    const int P = in_sizes[0] / 2;  // 262144

    double* accum = (double*)((char*)d_ws + WS_ACC_OFF);
    unsigned long long* packed = (unsigned long long*)((char*)d_ws + WS_PACKED_OFF);
    float* bto = (float*)((char*)d_ws + WS_BTO_OFF);

    // ws is poisoned 0xAA and never re-poisoned: zero accumulators + packed every call
    hipMemsetAsync(d_ws, 0, WS_BTO_OFF, stream);

    const int blocks = P / (256 * PPT);  // 256 blocks, 1 per CU
    apb_main<<<blocks, 256, 0, stream>>>(locs, params, truths, bto, packed, accum);
    apb_final<<<1, 128, 0, stream>>>(params, bto, packed, accum, (float*)d_out);
}

// Round 2
// 81.705 us; speedup vs baseline: 3.9010x; 3.9010x over previous
//
#include <hip/hip_runtime.h>

#define T_CNT 128
#define IOU_TH 0.4f
#define K_CONST 2.5f
#define PPT1 2   // priors/thread in kernel A
#define NP2 4    // priors/thread in kernel B
#define TG 16    // truths/block in kernel B

// ws layout:
//   [0,32)        double accum[3]: S1=sum(sig), S2=sum(xf), S3=sum(sig*xf*log(bto))
//   [64,1088)     unsigned long long packed[128]: (iou_bits<<32) | ~prior_idx
//   [4096, +P*4)  float bto[P]
static const size_t WS_ACC_OFF = 0;
static const size_t WS_PACKED_OFF = 64;
static const size_t WS_BTO_OFF = 4096;

__device__ inline unsigned long long shflxor_u64(unsigned long long v, int m) {
    unsigned int lo = (unsigned int)v;
    unsigned int hi = (unsigned int)(v >> 32);
    lo = __shfl_xor(lo, m, 64);
    hi = __shfl_xor(hi, m, 64);
    return ((unsigned long long)hi << 32) | lo;
}

// ---------------- Kernel A: per-prior best_truth_overlap + baseline sums ----
// Pure-VALU inner loop: prior in regs, truth broadcast from LDS, running max
// in regs. Reductions only in the epilogue.
__global__ __launch_bounds__(256) void apb_bto(
    const float* __restrict__ locs, const float* __restrict__ params,
    const float* __restrict__ truths, float* __restrict__ bto,
    double* __restrict__ accum)
{
    __shared__ float4 s_tb[T_CNT];
    __shared__ float  s_ta[T_CNT];

    const int tid = threadIdx.x;
    for (int t = tid; t < T_CNT; t += 256) {
        float4 tb = ((const float4*)truths)[t];
        s_tb[t] = tb;
        s_ta[t] = (tb.z - tb.x) * (tb.w - tb.y);
    }
    __syncthreads();

    const int base = blockIdx.x * (256 * PPT1);

    float px1[PPT1], py1[PPT1], px2[PPT1], py2[PPT1], parea[PPT1];
#pragma unroll
    for (int k = 0; k < PPT1; ++k) {
        int p = base + k * 256 + tid;
        float2 c = ((const float2*)locs)[p];
        float w = params[3 * p];
        float h = params[3 * p + 1];
        float hw = 0.5f * w, hh = 0.5f * h;
        px1[k] = c.x - hw; py1[k] = c.y - hh;
        px2[k] = c.x + hw; py2[k] = c.y + hh;
        parea[k] = w * h;
    }

    float btmax[PPT1];
#pragma unroll
    for (int k = 0; k < PPT1; ++k) btmax[k] = 0.f;

#pragma unroll 4
    for (int t = 0; t < T_CNT; ++t) {
        float4 tb = s_tb[t];
        float  ta = s_ta[t];
#pragma unroll
        for (int k = 0; k < PPT1; ++k) {
            float lx = fmaxf(tb.x, px1[k]);
            float ly = fmaxf(tb.y, py1[k]);
            float rx = fminf(tb.z, px2[k]);
            float ry = fminf(tb.w, py2[k]);
            float w = fmaxf(rx - lx, 0.f);
            float h = fmaxf(ry - ly, 0.f);
            float inter = w * h;
            float denom = (ta + parea[k]) - inter;
            float iou = inter * __builtin_amdgcn_rcpf(denom);
            btmax[k] = fmaxf(btmax[k], iou);
        }
    }

    // Epilogue: baseline sums (pre-scatter)
    float s1 = 0.f, s2 = 0.f, s3 = 0.f;
#pragma unroll
    for (int k = 0; k < PPT1; ++k) {
        int p = base + k * 256 + tid;
        float a = params[3 * p + 2];
        float sig = 1.f / (1.f + expf(-a));
        float bt = btmax[k];
        float xf = (bt > IOU_TH) ? 1.f : 0.f;
        s1 += sig;
        s2 += xf;
        s3 += (xf > 0.f) ? sig * logf(bt) : 0.f;
        bto[p] = bt;
    }
#pragma unroll
    for (int off = 32; off; off >>= 1) {
        s1 += __shfl_xor(s1, off, 64);
        s2 += __shfl_xor(s2, off, 64);
        s3 += __shfl_xor(s3, off, 64);
    }
    __shared__ float s_red[3][4];
    const int wv = tid >> 6;
    if ((tid & 63) == 0) { s_red[0][wv] = s1; s_red[1][wv] = s2; s_red[2][wv] = s3; }
    __syncthreads();
    if (tid == 0) {
        atomicAdd(&accum[0], (double)(s_red[0][0] + s_red[0][1] + s_red[0][2] + s_red[0][3]));
        atomicAdd(&accum[1], (double)(s_red[1][0] + s_red[1][1] + s_red[1][2] + s_red[1][3]));
        atomicAdd(&accum[2], (double)(s_red[2][0] + s_red[2][1] + s_red[2][2] + s_red[2][3]));
    }
}

// ---------------- Kernel B: per-truth argmax over priors ------------------
// Truth-tiled (TG truths/block), register-resident running argmax per truth,
// single block reduction + atomicMax at the end.
__global__ __launch_bounds__(256) void apb_argmax(
    const float* __restrict__ locs, const float* __restrict__ params,
    const float* __restrict__ truths, unsigned long long* __restrict__ packed)
{
    __shared__ float4 s_tb[TG];
    __shared__ float  s_ta[TG];
    __shared__ unsigned long long s_red[4][TG];

    const int tid = threadIdx.x;
    const int tbase = blockIdx.y * TG;
    if (tid < TG) {
        float4 tb = ((const float4*)truths)[tbase + tid];
        s_tb[tid] = tb;
        s_ta[tid] = (tb.z - tb.x) * (tb.w - tb.y);
    }
    __syncthreads();

    const int pbase = blockIdx.x * (256 * NP2);

    float px1[NP2], py1[NP2], px2[NP2], py2[NP2], parea[NP2];
#pragma unroll
    for (int i = 0; i < NP2; ++i) {
        int p = pbase + i * 256 + tid;
        float2 c = ((const float2*)locs)[p];
        float w = params[3 * p];
        float h = params[3 * p + 1];
        float hw = 0.5f * w, hh = 0.5f * h;
        px1[i] = c.x - hw; py1[i] = c.y - hh;
        px2[i] = c.x + hw; py2[i] = c.y + hh;
        parea[i] = w * h;
    }

    float maxv[TG];
    unsigned int maxi[TG];
#pragma unroll
    for (int g = 0; g < TG; ++g) { maxv[g] = -1.f; maxi[g] = 0u; }

#pragma unroll
    for (int g = 0; g < TG; ++g) {
        float4 tb = s_tb[g];
        float  ta = s_ta[g];
#pragma unroll
        for (int i = 0; i < NP2; ++i) {
            float lx = fmaxf(tb.x, px1[i]);
            float ly = fmaxf(tb.y, py1[i]);
            float rx = fminf(tb.z, px2[i]);
            float ry = fminf(tb.w, py2[i]);
            float w = fmaxf(rx - lx, 0.f);
            float h = fmaxf(ry - ly, 0.f);
            float inter = w * h;
            float denom = (ta + parea[i]) - inter;
            float iou = inter * __builtin_amdgcn_rcpf(denom);
            // strict > keeps first occurrence (smallest p within thread)
            if (iou > maxv[g]) {
                maxv[g] = iou;
                maxi[g] = (unsigned int)(pbase + i * 256 + tid);
            }
        }
    }

    const int wv = tid >> 6;
#pragma unroll
    for (int g = 0; g < TG; ++g) {
        unsigned long long v =
            ((unsigned long long)__float_as_uint(maxv[g]) << 32) |
            (unsigned long long)(~maxi[g]);
#pragma unroll
        for (int off = 32; off; off >>= 1) {
            unsigned long long o = shflxor_u64(v, off);
            v = (o > v) ? o : v;
        }
        if ((tid & 63) == 0) s_red[wv][g] = v;
    }
    __syncthreads();
    if (tid < TG) {
        unsigned long long v = s_red[0][tid];
        unsigned long long o1 = s_red[1][tid];
        unsigned long long o2 = s_red[2][tid];
        unsigned long long o3 = s_red[3][tid];
        v = (o1 > v) ? o1 : v;
        v = (o2 > v) ? o2 : v;
        v = (o3 > v) ? o3 : v;
        atomicMax(&packed[tbase + tid], v);
    }
}

// ---------------- Finalize: scatter corrections + scalar loss --------------
__global__ __launch_bounds__(128) void apb_final(
    const float* __restrict__ params, const float* __restrict__ bto,
    const unsigned long long* __restrict__ packed,
    const double* __restrict__ accum, float* __restrict__ out)
{
    const int t = threadIdx.x;
    __shared__ unsigned int s_idx[T_CNT];

    unsigned long long v = packed[t];
    float ov = __uint_as_float((unsigned int)(v >> 32));     // best_prior_overlap[t]
    unsigned int p = ~(unsigned int)(v & 0xFFFFFFFFull);     // best_prior_idx[t]
    s_idx[t] = p;
    __syncthreads();

    // numpy fancy-assignment semantics: for duplicate indices, last t wins
    bool is_last = true;
    for (int u = t + 1; u < T_CNT; ++u)
        if (s_idx[u] == p) is_last = false;

    float c2 = 0.f, c3 = 0.f;
    if (is_last) {
        float old = bto[p];
        float oxf = (old > IOU_TH) ? 1.f : 0.f;
        float a = params[3 * p + 2];
        float sig = 1.f / (1.f + expf(-a));
        float oldterm = (oxf > 0.f) ? sig * logf(old) : 0.f;
        float newterm = K_CONST * sig * logf(ov);
        c3 = newterm - oldterm;
        c2 = K_CONST - oxf;
    }

#pragma unroll
    for (int off = 32; off; off >>= 1) {
        c2 += __shfl_xor(c2, off, 64);
        c3 += __shfl_xor(c3, off, 64);
    }
    __shared__ float sw[4];
    if ((t & 63) == 0) { sw[(t >> 6) * 2] = c2; sw[(t >> 6) * 2 + 1] = c3; }
    __syncthreads();

    if (t == 0) {
        double S1 = accum[0];
        double S2 = accum[1] + (double)(sw[0] + sw[2]);
        double S3 = accum[2] + (double)(sw[1] + sw[3]);
        out[0] = (float)((S1 - S3) / S2);  // BETA = 1.0
    }
}

extern "C" void kernel_launch(void* const* d_in, const int* in_sizes, int n_in,
                              void* d_out, int out_size, void* d_ws, size_t ws_size,
                              hipStream_t stream) {
    const float* locs   = (const float*)d_in[0];
    const float* params = (const float*)d_in[1];
    const float* truths = (const float*)d_in[2];
    const int P = in_sizes[0] / 2;  // 262144

    double* accum = (double*)((char*)d_ws + WS_ACC_OFF);
    unsigned long long* packed = (unsigned long long*)((char*)d_ws + WS_PACKED_OFF);
    float* bto = (float*)((char*)d_ws + WS_BTO_OFF);

    // ws is poisoned 0xAA and never re-poisoned: zero accum + packed every call
    hipMemsetAsync(d_ws, 0, WS_BTO_OFF, stream);

    apb_bto<<<P / (256 * PPT1), 256, 0, stream>>>(locs, params, truths, bto, accum);
    dim3 g2(P / (256 * NP2), T_CNT / TG);
    apb_argmax<<<g2, 256, 0, stream>>>(locs, params, truths, packed);
    apb_final<<<1, 128, 0, stream>>>(params, bto, packed, accum, (float*)d_out);
}

// Round 3
// 72.096 us; speedup vs baseline: 4.4209x; 1.1333x over previous
//
#include <hip/hip_runtime.h>

#define T_CNT 128
#define IOU_TH 0.4f
#define K_CONST 2.5f
#define PPT1 2   // priors/thread in kernel A
#define NP2 4    // priors/thread in kernel B
#define TG 16    // truths/block in kernel B

// ws layout:
//   [0,32)        double accum[3]: S1=sum(sig), S2=sum(xf), S3=sum(sig*xf*log(bto))
//   [64,1088)     unsigned long long packed[128]: (iou_bits<<32) | ~prior_idx
//   [4096, +P*4)  float bto[P]
static const size_t WS_ACC_OFF = 0;
static const size_t WS_PACKED_OFF = 64;
static const size_t WS_BTO_OFF = 4096;

__device__ inline unsigned long long shflxor_u64(unsigned long long v, int m) {
    unsigned int lo = (unsigned int)v;
    unsigned int hi = (unsigned int)(v >> 32);
    lo = __shfl_xor(lo, m, 64);
    hi = __shfl_xor(hi, m, 64);
    return ((unsigned long long)hi << 32) | lo;
}

// ---------------- Kernel A: per-prior best_truth_overlap + baseline sums ----
__global__ __launch_bounds__(256) void apb_bto(
    const float* __restrict__ locs, const float* __restrict__ params,
    const float* __restrict__ truths, float* __restrict__ bto,
    double* __restrict__ accum)
{
    __shared__ float4 s_tb[T_CNT];
    __shared__ float  s_ta[T_CNT];

    const int tid = threadIdx.x;
    for (int t = tid; t < T_CNT; t += 256) {
        float4 tb = ((const float4*)truths)[t];
        s_tb[t] = tb;
        s_ta[t] = (tb.z - tb.x) * (tb.w - tb.y);
    }
    __syncthreads();

    const int base = blockIdx.x * (256 * PPT1);

    float px1[PPT1], py1[PPT1], px2[PPT1], py2[PPT1], parea[PPT1];
#pragma unroll
    for (int k = 0; k < PPT1; ++k) {
        int p = base + k * 256 + tid;
        float2 c = ((const float2*)locs)[p];
        float w = params[3 * p];
        float h = params[3 * p + 1];
        float hw = 0.5f * w, hh = 0.5f * h;
        px1[k] = c.x - hw; py1[k] = c.y - hh;
        px2[k] = c.x + hw; py2[k] = c.y + hh;
        parea[k] = w * h;
    }

    float btmax[PPT1];
#pragma unroll
    for (int k = 0; k < PPT1; ++k) btmax[k] = 0.f;

#pragma unroll 4
    for (int t = 0; t < T_CNT; ++t) {
        float4 tb = s_tb[t];
        float  ta = s_ta[t];
#pragma unroll
        for (int k = 0; k < PPT1; ++k) {
            float lx = fmaxf(tb.x, px1[k]);
            float ly = fmaxf(tb.y, py1[k]);
            float rx = fminf(tb.z, px2[k]);
            float ry = fminf(tb.w, py2[k]);
            float w = fmaxf(rx - lx, 0.f);
            float h = fmaxf(ry - ly, 0.f);
            float inter = w * h;
            float denom = (ta + parea[k]) - inter;
            float iou = inter * __builtin_amdgcn_rcpf(denom);
            btmax[k] = fmaxf(btmax[k], iou);
        }
    }

    float s1 = 0.f, s2 = 0.f, s3 = 0.f;
#pragma unroll
    for (int k = 0; k < PPT1; ++k) {
        int p = base + k * 256 + tid;
        float a = params[3 * p + 2];
        float sig = 1.f / (1.f + expf(-a));
        float bt = btmax[k];
        float xf = (bt > IOU_TH) ? 1.f : 0.f;
        s1 += sig;
        s2 += xf;
        s3 += (xf > 0.f) ? sig * logf(bt) : 0.f;
        bto[p] = bt;
    }
#pragma unroll
    for (int off = 32; off; off >>= 1) {
        s1 += __shfl_xor(s1, off, 64);
        s2 += __shfl_xor(s2, off, 64);
        s3 += __shfl_xor(s3, off, 64);
    }
    __shared__ float s_red[3][4];
    const int wv = tid >> 6;
    if ((tid & 63) == 0) { s_red[0][wv] = s1; s_red[1][wv] = s2; s_red[2][wv] = s3; }
    __syncthreads();
    if (tid == 0) {
        atomicAdd(&accum[0], (double)(s_red[0][0] + s_red[0][1] + s_red[0][2] + s_red[0][3]));
        atomicAdd(&accum[1], (double)(s_red[1][0] + s_red[1][1] + s_red[1][2] + s_red[1][3]));
        atomicAdd(&accum[2], (double)(s_red[2][0] + s_red[2][1] + s_red[2][2] + s_red[2][3]));
    }
}

// ---------------- Kernel B: per-truth argmax over priors ------------------
// Truth-tiled, register-resident running argmax, LDS-staged two-level reduce
// (no butterfly chains in or after the hot loop).
__global__ __launch_bounds__(256) void apb_argmax(
    const float* __restrict__ locs, const float* __restrict__ params,
    const float* __restrict__ truths, unsigned long long* __restrict__ packed)
{
    __shared__ float4 s_tb[TG];
    __shared__ float  s_ta[TG];
    __shared__ unsigned long long s_cand[TG][256];  // 32 KB

    const int tid = threadIdx.x;
    const int tbase = blockIdx.y * TG;
    if (tid < TG) {
        float4 tb = ((const float4*)truths)[tbase + tid];
        s_tb[tid] = tb;
        s_ta[tid] = (tb.z - tb.x) * (tb.w - tb.y);
    }
    __syncthreads();

    const int pbase = blockIdx.x * (256 * NP2);

    float px1[NP2], py1[NP2], px2[NP2], py2[NP2], parea[NP2];
#pragma unroll
    for (int i = 0; i < NP2; ++i) {
        int p = pbase + i * 256 + tid;
        float2 c = ((const float2*)locs)[p];
        float w = params[3 * p];
        float h = params[3 * p + 1];
        float hw = 0.5f * w, hh = 0.5f * h;
        px1[i] = c.x - hw; py1[i] = c.y - hh;
        px2[i] = c.x + hw; py2[i] = c.y + hh;
        parea[i] = w * h;
    }

    float maxv[TG];
    unsigned int maxi[TG];
#pragma unroll
    for (int g = 0; g < TG; ++g) { maxv[g] = -1.f; maxi[g] = 0u; }

#pragma unroll
    for (int g = 0; g < TG; ++g) {
        float4 tb = s_tb[g];
        float  ta = s_ta[g];
#pragma unroll
        for (int i = 0; i < NP2; ++i) {
            float lx = fmaxf(tb.x, px1[i]);
            float ly = fmaxf(tb.y, py1[i]);
            float rx = fminf(tb.z, px2[i]);
            float ry = fminf(tb.w, py2[i]);
            float w = fmaxf(rx - lx, 0.f);
            float h = fmaxf(ry - ly, 0.f);
            float inter = w * h;
            float denom = (ta + parea[i]) - inter;
            float iou = inter * __builtin_amdgcn_rcpf(denom);
            if (iou > maxv[g]) {   // strict > keeps smallest p within thread
                maxv[g] = iou;
                maxi[g] = (unsigned int)(pbase + i * 256 + tid);
            }
        }
    }

    // stage 1: all candidates to LDS
#pragma unroll
    for (int g = 0; g < TG; ++g)
        s_cand[g][tid] = ((unsigned long long)__float_as_uint(maxv[g]) << 32) |
                         (unsigned long long)(~maxi[g]);
    __syncthreads();

    // stage 2: 16 threads per truth, each serially reduces 16 independent reads.
    // Rotated index (j+s)&15 avoids the 32-way same-bank pattern.
    {
        const int g = tid >> 4;
        const int s = tid & 15;
        unsigned long long m = 0ull;
#pragma unroll
        for (int j = 0; j < 16; ++j) {
            unsigned long long c = s_cand[g][s * 16 + ((j + s) & 15)];
            m = (c > m) ? c : m;
        }
        // stage 3: 4-step shuffle reduce within the 16-lane group
#pragma unroll
        for (int off = 1; off <= 8; off <<= 1) {
            unsigned long long o = shflxor_u64(m, off);
            m = (o > m) ? o : m;
        }
        if (s == 0) atomicMax(&packed[tbase + g], m);
    }
}

// ---------------- Finalize: scatter corrections + scalar loss --------------
__global__ __launch_bounds__(128) void apb_final(
    const float* __restrict__ params, const float* __restrict__ bto,
    const unsigned long long* __restrict__ packed,
    const double* __restrict__ accum, float* __restrict__ out)
{
    const int t = threadIdx.x;
    __shared__ unsigned int s_idx[T_CNT];

    unsigned long long v = packed[t];
    float ov = __uint_as_float((unsigned int)(v >> 32));     // best_prior_overlap[t]
    unsigned int p = ~(unsigned int)(v & 0xFFFFFFFFull);     // best_prior_idx[t]
    s_idx[t] = p;
    __syncthreads();

    // numpy fancy-assignment semantics: for duplicate indices, last t wins
    bool is_last = true;
    for (int u = t + 1; u < T_CNT; ++u)
        if (s_idx[u] == p) is_last = false;

    float c2 = 0.f, c3 = 0.f;
    if (is_last && v != 0ull) {
        float old = bto[p];
        float oxf = (old > IOU_TH) ? 1.f : 0.f;
        float a = params[3 * p + 2];
        float sig = 1.f / (1.f + expf(-a));
        float oldterm = (oxf > 0.f) ? sig * logf(old) : 0.f;
        float newterm = K_CONST * sig * logf(ov);
        c3 = newterm - oldterm;
        c2 = K_CONST - oxf;
    }

#pragma unroll
    for (int off = 32; off; off >>= 1) {
        c2 += __shfl_xor(c2, off, 64);
        c3 += __shfl_xor(c3, off, 64);
    }
    __shared__ float sw[4];
    if ((t & 63) == 0) { sw[(t >> 6) * 2] = c2; sw[(t >> 6) * 2 + 1] = c3; }
    __syncthreads();

    if (t == 0) {
        double S1 = accum[0];
        double S2 = accum[1] + (double)(sw[0] + sw[2]);
        double S3 = accum[2] + (double)(sw[1] + sw[3]);
        out[0] = (float)((S1 - S3) / S2);  // BETA = 1.0
    }
}

extern "C" void kernel_launch(void* const* d_in, const int* in_sizes, int n_in,
                              void* d_out, int out_size, void* d_ws, size_t ws_size,
                              hipStream_t stream) {
    const float* locs   = (const float*)d_in[0];
    const float* params = (const float*)d_in[1];
    const float* truths = (const float*)d_in[2];
    const int P = in_sizes[0] / 2;  // 262144

    double* accum = (double*)((char*)d_ws + WS_ACC_OFF);
    unsigned long long* packed = (unsigned long long*)((char*)d_ws + WS_PACKED_OFF);
    float* bto = (float*)((char*)d_ws + WS_BTO_OFF);

    // ws is poisoned 0xAA and never re-poisoned: zero accum + packed every call
    hipMemsetAsync(d_ws, 0, WS_BTO_OFF, stream);

    apb_bto<<<P / (256 * PPT1), 256, 0, stream>>>(locs, params, truths, bto, accum);
    dim3 g2(P / (256 * NP2), T_CNT / TG);
    apb_argmax<<<g2, 256, 0, stream>>>(locs, params, truths, packed);
    apb_final<<<1, 128, 0, stream>>>(params, bto, packed, accum, (float*)d_out);
}

// Round 4
// 53.093 us; speedup vs baseline: 6.0032x; 1.3579x over previous
//
#include <hip/hip_runtime.h>

#define T_CNT 128
#define IOU_TH 0.4f
#define K_CONST 2.5f
#define PPT 2           // priors per thread
#define TG 16           // truths per group
#define NGRP (T_CNT / TG)

// ws layout:
//   [0,32)        double accum[3]: S1=sum(sig), S2=sum(xf), S3=sum(sig*xf*log(bto))
//   [64,1088)     unsigned long long packed[128]: (iou_bits<<32) | ~prior_idx
//   [4096, +P*4)  float bto[P]
static const size_t WS_ACC_OFF = 0;
static const size_t WS_PACKED_OFF = 64;
static const size_t WS_BTO_OFF = 4096;

__device__ inline unsigned long long shflxor_u64(unsigned long long v, int m) {
    unsigned int lo = (unsigned int)v;
    unsigned int hi = (unsigned int)(v >> 32);
    lo = __shfl_xor(lo, m, 64);
    hi = __shfl_xor(hi, m, 64);
    return ((unsigned long long)hi << 32) | lo;
}

// ---- Fused kernel: one pass over the IoU matrix, both reductions ----------
// Per block: 512 priors (PPT=2). Outer loop over 8 groups of 16 truths.
// Register argmax (static-indexed, fully unrolled) + per-prior running max
// share each IoU. Per group: LDS-staged two-level argmax reduce + atomicMax.
__global__ __launch_bounds__(256) void apb_fused(
    const float* __restrict__ locs, const float* __restrict__ params,
    const float* __restrict__ truths, float* __restrict__ bto,
    unsigned long long* __restrict__ packed, double* __restrict__ accum)
{
    __shared__ float4 s_tb[T_CNT];
    __shared__ float  s_ta[T_CNT];
    __shared__ unsigned long long s_cand[TG][256];  // 32 KB, reused per group
    __shared__ float s_red[3][4];

    const int tid = threadIdx.x;
    if (tid < T_CNT) {
        float4 tb = ((const float4*)truths)[tid];
        s_tb[tid] = tb;
        s_ta[tid] = (tb.z - tb.x) * (tb.w - tb.y);
    }
    __syncthreads();

    const int base = blockIdx.x * (256 * PPT);

    float px1[PPT], py1[PPT], px2[PPT], py2[PPT], parea[PPT];
    unsigned int pidx[PPT];
#pragma unroll
    for (int k = 0; k < PPT; ++k) {
        int p = base + k * 256 + tid;
        float2 c = ((const float2*)locs)[p];
        float w = params[3 * p];
        float h = params[3 * p + 1];
        float hw = 0.5f * w, hh = 0.5f * h;
        px1[k] = c.x - hw; py1[k] = c.y - hh;
        px2[k] = c.x + hw; py2[k] = c.y + hh;
        parea[k] = w * h;
        pidx[k] = (unsigned int)p;
    }

    float btmax[PPT];
#pragma unroll
    for (int k = 0; k < PPT; ++k) btmax[k] = 0.f;

    for (int grp = 0; grp < NGRP; ++grp) {
        float maxv[TG];
        unsigned int maxi[TG];
#pragma unroll
        for (int g = 0; g < TG; ++g) { maxv[g] = -1.f; maxi[g] = 0u; }

#pragma unroll
        for (int g = 0; g < TG; ++g) {
            int t = grp * TG + g;
            float4 tb = s_tb[t];
            float  ta = s_ta[t];
#pragma unroll
            for (int k = 0; k < PPT; ++k) {
                float lx = fmaxf(tb.x, px1[k]);
                float ly = fmaxf(tb.y, py1[k]);
                float rx = fminf(tb.z, px2[k]);
                float ry = fminf(tb.w, py2[k]);
                float w = fmaxf(rx - lx, 0.f);
                float h = fmaxf(ry - ly, 0.f);
                float inter = w * h;
                float denom = (ta + parea[k]) - inter;
                float iou = inter * __builtin_amdgcn_rcpf(denom);
                btmax[k] = fmaxf(btmax[k], iou);
                if (iou > maxv[g]) {  // strict > keeps smallest p per thread
                    maxv[g] = iou;
                    maxi[g] = pidx[k];
                }
            }
        }

        __syncthreads();  // previous group's readers done with s_cand
#pragma unroll
        for (int g = 0; g < TG; ++g)
            s_cand[g][tid] =
                ((unsigned long long)__float_as_uint(maxv[g]) << 32) |
                (unsigned long long)(~maxi[g]);
        __syncthreads();

        // two-level reduce: 16 threads/truth, rotated reads (bank-spread),
        // then 4-step 16-lane shuffle reduce, one atomicMax per truth.
        {
            const int g = tid >> 4;
            const int s = tid & 15;
            unsigned long long m = 0ull;
#pragma unroll
            for (int j = 0; j < 16; ++j) {
                unsigned long long c = s_cand[g][s * 16 + ((j + s) & 15)];
                m = (c > m) ? c : m;
            }
#pragma unroll
            for (int off = 1; off <= 8; off <<= 1) {
                unsigned long long o = shflxor_u64(m, off);
                m = (o > m) ? o : m;
            }
            if (s == 0) atomicMax(&packed[grp * TG + g], m);
        }
    }

    // Epilogue: per-prior loss terms (pre-scatter baseline) + bto write
    float s1 = 0.f, s2 = 0.f, s3 = 0.f;
#pragma unroll
    for (int k = 0; k < PPT; ++k) {
        int p = base + k * 256 + tid;
        float a = params[3 * p + 2];
        float sig = 1.f / (1.f + expf(-a));
        float bt = btmax[k];
        float xf = (bt > IOU_TH) ? 1.f : 0.f;
        s1 += sig;
        s2 += xf;
        s3 += (xf > 0.f) ? sig * logf(bt) : 0.f;
        bto[p] = bt;
    }
#pragma unroll
    for (int off = 32; off; off >>= 1) {
        s1 += __shfl_xor(s1, off, 64);
        s2 += __shfl_xor(s2, off, 64);
        s3 += __shfl_xor(s3, off, 64);
    }
    const int wv = tid >> 6;
    if ((tid & 63) == 0) { s_red[0][wv] = s1; s_red[1][wv] = s2; s_red[2][wv] = s3; }
    __syncthreads();
    if (tid == 0) {
        atomicAdd(&accum[0], (double)(s_red[0][0] + s_red[0][1] + s_red[0][2] + s_red[0][3]));
        atomicAdd(&accum[1], (double)(s_red[1][0] + s_red[1][1] + s_red[1][2] + s_red[1][3]));
        atomicAdd(&accum[2], (double)(s_red[2][0] + s_red[2][1] + s_red[2][2] + s_red[2][3]));
    }
}

// ---------------- Finalize: scatter corrections + scalar loss --------------
__global__ __launch_bounds__(128) void apb_final(
    const float* __restrict__ params, const float* __restrict__ bto,
    const unsigned long long* __restrict__ packed,
    const double* __restrict__ accum, float* __restrict__ out)
{
    const int t = threadIdx.x;
    __shared__ unsigned int s_idx[T_CNT];

    unsigned long long v = packed[t];
    float ov = __uint_as_float((unsigned int)(v >> 32));     // best_prior_overlap[t]
    unsigned int p = ~(unsigned int)(v & 0xFFFFFFFFull);     // best_prior_idx[t]
    s_idx[t] = p;
    __syncthreads();

    // numpy fancy-assignment semantics: duplicate indices -> last t wins
    bool is_last = true;
    for (int u = t + 1; u < T_CNT; ++u)
        if (s_idx[u] == p) is_last = false;

    float c2 = 0.f, c3 = 0.f;
    if (is_last && v != 0ull) {
        float old = bto[p];
        float oxf = (old > IOU_TH) ? 1.f : 0.f;
        float a = params[3 * p + 2];
        float sig = 1.f / (1.f + expf(-a));
        float oldterm = (oxf > 0.f) ? sig * logf(old) : 0.f;
        float newterm = K_CONST * sig * logf(ov);
        c3 = newterm - oldterm;
        c2 = K_CONST - oxf;
    }

#pragma unroll
    for (int off = 32; off; off >>= 1) {
        c2 += __shfl_xor(c2, off, 64);
        c3 += __shfl_xor(c3, off, 64);
    }
    __shared__ float sw[4];
    if ((t & 63) == 0) { sw[(t >> 6) * 2] = c2; sw[(t >> 6) * 2 + 1] = c3; }
    __syncthreads();

    if (t == 0) {
        double S1 = accum[0];
        double S2 = accum[1] + (double)(sw[0] + sw[2]);
        double S3 = accum[2] + (double)(sw[1] + sw[3]);
        out[0] = (float)((S1 - S3) / S2);  // BETA = 1.0
    }
}

extern "C" void kernel_launch(void* const* d_in, const int* in_sizes, int n_in,
                              void* d_out, int out_size, void* d_ws, size_t ws_size,
                              hipStream_t stream) {
    const float* locs   = (const float*)d_in[0];
    const float* params = (const float*)d_in[1];
    const float* truths = (const float*)d_in[2];
    const int P = in_sizes[0] / 2;  // 262144

    double* accum = (double*)((char*)d_ws + WS_ACC_OFF);
    unsigned long long* packed = (unsigned long long*)((char*)d_ws + WS_PACKED_OFF);
    float* bto = (float*)((char*)d_ws + WS_BTO_OFF);

    // ws is poisoned 0xAA and never re-poisoned: zero accum + packed each call
    hipMemsetAsync(d_ws, 0, 1088, stream);

    apb_fused<<<P / (256 * PPT), 256, 0, stream>>>(locs, params, truths, bto, packed, accum);
    apb_final<<<1, 128, 0, stream>>>(params, bto, packed, accum, (float*)d_out);
}